// Round 10
// baseline (8258.501 us; speedup 1.0000x reference)
//
#include <hip/hip_runtime.h>
#include <stdint.h>

typedef unsigned short u16;
typedef __bf16 bf16x8 __attribute__((ext_vector_type(8)));
typedef float f32x4 __attribute__((ext_vector_type(4)));

#define MT 16384   // BATCH*SEQ tokens

__device__ __forceinline__ u16 f2bf(float f) {
  union { float f; unsigned u; } x; x.f = f;
  unsigned r = x.u + 0x7fffu + ((x.u >> 16) & 1u);   // RNE
  return (u16)(r >> 16);
}

#pragma clang diagnostic push
#pragma clang diagnostic ignored "-Waddress-space-conversion"
typedef __attribute__((address_space(1))) unsigned as1u;
typedef __attribute__((address_space(3))) unsigned as3u;
// async global->LDS, 16B per lane; lbase must be wave-uniform (HW adds lane*16)
__device__ __forceinline__ void stage16(const u16* g, const u16* lbase) {
  __builtin_amdgcn_global_load_lds((as1u*)g, (as3u*)lbase, 16, 0, 0);
}
#pragma clang diagnostic pop

// ---------------- weight transpose + f32->bf16 convert ----------------
__global__ void __launch_bounds__(256)
transpose_cvt(const float* __restrict__ in, u16* __restrict__ out, int K, int N) {
  __shared__ float tile[32][33];
  const int k0 = blockIdx.y * 32, n0 = blockIdx.x * 32;
  const int tx = threadIdx.x, ty = threadIdx.y;   // block (32,8)
  #pragma unroll
  for (int r = 0; r < 32; r += 8)
    tile[ty + r][tx] = in[(size_t)(k0 + ty + r) * N + n0 + tx];
  __syncthreads();
  #pragma unroll
  for (int r = 0; r < 32; r += 8)
    out[(size_t)(n0 + ty + r) * K + k0 + tx] = f2bf(tile[tx][ty + r]);
}

// ---------------- embedding: x = tok_emb[idx] + pos_emb ----------------
__global__ void __launch_bounds__(256)
embed_kernel(const int* __restrict__ idx, const float* __restrict__ tok,
             const float* __restrict__ pos, float* __restrict__ x,
             u16* __restrict__ xb) {
  const int tk = blockIdx.x;
  const int s = tk & 63;
  const int id = idx[tk];
  const int t = threadIdx.x;
  float4 a = ((const float4*)(tok + (size_t)id * 1024))[t];
  float4 p = ((const float4*)(pos + (size_t)s * 1024))[t];
  float4 r; r.x = a.x + p.x; r.y = a.y + p.y; r.z = a.z + p.z; r.w = a.w + p.w;
  ((float4*)(x + (size_t)tk * 1024))[t] = r;
  u16* o = xb + (size_t)tk * 1024 + t * 4;
  o[0] = f2bf(r.x); o[1] = f2bf(r.y); o[2] = f2bf(r.z); o[3] = f2bf(r.w);
}

// ---------------- 128x128 GEMM: C = A[M][K](bf16) @ Bt[N][K]^T + bias ----------------
// R9's verified geometry (4 waves 2x2, BK=32, packed-pair 0-conflict swizzle,
// 3 blocks/CU) with the ONE change: TRIPLE-buffered LDS + stage-2-tiles-AHEAD +
// raw s_barrier + counted vmcnt(4) per K-step (T3+T4). Ledger: step u's buf was
// staged at step u-2 (~2 steps of latency cover); vmcnt(4) leaves exactly step
// u-1's 4 loads in flight. WAR on buf[(u+2)%3]: old tile last read at step u-1,
// and every wave executed lgkmcnt(0) before the current barrier. Uniform 4
// stages/step (wrap-refetch at the tail keeps the vmcnt count exact).
// EPI 0: out bf16 | 1: gelu->bf16 | 2: +res(f32), write f32+bf16 | 3: out f32
template<int EPI>
__global__ void __launch_bounds__(256, 3)
gemm128(const u16* __restrict__ A, const u16* __restrict__ Bt,
        const float* __restrict__ bias, float* __restrict__ resf,
        u16* __restrict__ outb, float* __restrict__ outf,
        int M, int N, int K, int gn) {
  __shared__ __align__(16) u16 lA[3][4096];   // 128 rows x 32 k bf16 per buffer
  __shared__ __align__(16) u16 lB[3][4096];
  const int t = threadIdx.x;
  const int lane = t & 63, w = t >> 6;        // 4 waves: (wr,wc) 2x2
  const int wr = w >> 1, wc = w & 1;
  const int fr = lane & 15, fg = lane >> 4;

  // XCD swizzle (grid %8==0) + tn-fastest decomposition for A-panel L2 reuse
  const int nwg = gridDim.x;
  const int bid = blockIdx.x;
  const int s = (bid & 7) * (nwg >> 3) + (bid >> 3);
  const int tn = s % gn, tm = s / gn;
  const int m0 = tm * 128, n0 = tn * 128;

  // staging source mapping (inverse of packed-pair swizzle); chunk = 16 rows = 1KB
  const int rin = ((lane >> 3) << 1) + ((lane >> 2) & 1);   // row within chunk
  const int fgl = (lane & 3) ^ ((lane >> 3) & 3);           // logical k-granule
  const u16* gA[2]; const u16* gB[2];
  #pragma unroll
  for (int i = 0; i < 2; ++i) {
    gA[i] = A  + (size_t)(m0 + (w * 2 + i) * 16 + rin) * K + fgl * 8;
    gB[i] = Bt + (size_t)(n0 + (w * 2 + i) * 16 + rin) * K + fgl * 8;
  }

  // LDS read offsets (u16 units): chunk*512 + line*64 + sub8
  const int sub8 = ((fr & 1) * 4 + (fg ^ ((fr >> 1) & 3))) * 8;
  const int ar = wr * 2048 + (fr >> 1) * 64 + sub8;   // + m*512
  const int br = wc * 2048 + (fr >> 1) * 64 + sub8;   // + n*512

  f32x4 acc[4][4] = {};
  const int NT = K >> 5;

  // prologue: tiles 0,1 -> bufs 0,1 (issue order = ledger order)
  #pragma unroll
  for (int i = 0; i < 2; ++i) {
    stage16(gA[i], &lA[0][(w * 2 + i) * 512]);
    stage16(gB[i], &lB[0][(w * 2 + i) * 512]);
  }
  #pragma unroll
  for (int i = 0; i < 2; ++i) {
    stage16(gA[i] + 32, &lA[1][(w * 2 + i) * 512]);
    stage16(gB[i] + 32, &lB[1][(w * 2 + i) * 512]);
  }

  int cur = 0, nb = 2;
  for (int u = 0; u < NT; ++u) {
    asm volatile("s_waitcnt vmcnt(4)" ::: "memory");   // publish buf[cur]
    __builtin_amdgcn_s_barrier();

    bf16x8 af[4], bv[4];
    #pragma unroll
    for (int m = 0; m < 4; ++m) af[m] = *(const bf16x8*)&lA[cur][ar + m * 512];
    #pragma unroll
    for (int n = 0; n < 4; ++n) bv[n] = *(const bf16x8*)&lB[cur][br + n * 512];
    #pragma unroll
    for (int m = 0; m < 4; ++m)
      #pragma unroll
      for (int n = 0; n < 4; ++n)
        acc[m][n] = __builtin_amdgcn_mfma_f32_16x16x32_bf16(af[m], bv[n], acc[m][n], 0, 0, 0);

    asm volatile("s_waitcnt lgkmcnt(0)" ::: "memory"); // my reads of buf[nb]'s old tile done
    const int kt = u + 2;
    const int ko = (kt < NT ? kt : kt - NT) << 5;      // wrap keeps ledger uniform
    #pragma unroll
    for (int i = 0; i < 2; ++i) {
      stage16(gA[i] + ko, &lA[nb][(w * 2 + i) * 512]);
      stage16(gB[i] + ko, &lB[nb][(w * 2 + i) * 512]);
    }
    cur = (cur == 2) ? 0 : cur + 1;
    nb  = (nb == 2) ? 0 : nb + 1;
  }

  #pragma unroll
  for (int m = 0; m < 4; ++m) {
    const int row = m0 + wr * 64 + m * 16 + fg * 4;
    #pragma unroll
    for (int n = 0; n < 4; ++n) {
      const int col = n0 + wc * 64 + n * 16 + fr;
      const float bc = bias[col];
      #pragma unroll
      for (int i = 0; i < 4; ++i) {
        const size_t off = (size_t)(row + i) * N + col;
        float v = acc[m][n][i] + bc;
        if constexpr (EPI == 0) {
          outb[off] = f2bf(v);
        } else if constexpr (EPI == 1) {
          v = 0.5f * v * (1.0f + erff(v * 0.70710678118654752f));
          outb[off] = f2bf(v);
        } else if constexpr (EPI == 2) {
          v += resf[off];
          resf[off] = v;
          outb[off] = f2bf(v);
        } else {
          outf[off] = v;
        }
      }
    }
  }
}

// ---------------- attention (one block per (b,h)) ----------------
__global__ void __launch_bounds__(256)
attn_kernel(const u16* __restrict__ qkv, u16* __restrict__ y) {
  __shared__ __align__(16) u16 qs[64][72];    // Q; reused as P (bf16)
  __shared__ __align__(16) u16 ks[64][72];
  __shared__ __align__(16) u16 vts[64][72];   // V transposed: [dh][key]
  __shared__ __align__(16) float S[64][68];   // [query][key] f32
  __shared__ float red[4][64];

  const int h = blockIdx.x, b = blockIdx.y;
  const int t = threadIdx.x;
  const int lane = t & 63, w = t >> 6;
  const int fr = lane & 15, fg = lane >> 4;

  #pragma unroll
  for (int it = 0; it < 2; ++it) {
    const int id = t + it * 256;           // 0..511
    const int row = id >> 3, seg = id & 7;
    const size_t gq = (size_t)(b * 64 + row) * 3072 + h * 64 + seg * 8;
    *(uint4*)&qs[row][seg * 8] = *(const uint4*)&qkv[gq];
    *(uint4*)&ks[row][seg * 8] = *(const uint4*)&qkv[gq + 1024];
  }
  {
    const int d = t & 63;
    #pragma unroll
    for (int it = 0; it < 16; ++it) {
      const int s = (t >> 6) + it * 4;
      vts[d][s] = qkv[(size_t)(b * 64 + s) * 3072 + 2048 + h * 64 + d];
    }
  }
  __syncthreads();

  f32x4 sa[4] = {};
  #pragma unroll
  for (int kk = 0; kk < 64; kk += 32) {
    bf16x8 qa = *(const bf16x8*)&qs[w * 16 + fr][kk + fg * 8];
    #pragma unroll
    for (int n = 0; n < 4; ++n) {
      bf16x8 kb = *(const bf16x8*)&ks[n * 16 + fr][kk + fg * 8];
      sa[n] = __builtin_amdgcn_mfma_f32_16x16x32_bf16(qa, kb, sa[n], 0, 0, 0);
    }
  }
  #pragma unroll
  for (int n = 0; n < 4; ++n)
    #pragma unroll
    for (int i = 0; i < 4; ++i) {
      const int row = w * 16 + fg * 4 + i, col = n * 16 + fr;
      S[row][col] = (row >= col) ? sa[n][i] * 0.03125f : -1e30f;
    }
  __syncthreads();

  const int c = t & 63, q4 = t >> 6;
  float mx = -1e30f;
  float e[16];
  #pragma unroll
  for (int i = 0; i < 16; ++i) mx = fmaxf(mx, S[q4 * 16 + i][c]);
  red[q4][c] = mx;
  __syncthreads();
  mx = fmaxf(fmaxf(red[0][c], red[1][c]), fmaxf(red[2][c], red[3][c]));
  float sum = 0.f;
  #pragma unroll
  for (int i = 0; i < 16; ++i) { e[i] = __expf(S[q4 * 16 + i][c] - mx); sum += e[i]; }
  __syncthreads();
  red[q4][c] = sum;
  __syncthreads();
  sum = red[0][c] + red[1][c] + red[2][c] + red[3][c];
  const float inv = 1.0f / sum;
  u16 (*P)[72] = qs;
  #pragma unroll
  for (int i = 0; i < 16; ++i)
    P[q4 * 16 + i][c] = f2bf(e[i] * inv);
  __syncthreads();

  f32x4 oa[4] = {};
  #pragma unroll
  for (int kk = 0; kk < 64; kk += 32) {
    bf16x8 pa = *(const bf16x8*)&P[w * 16 + fr][kk + fg * 8];
    #pragma unroll
    for (int n = 0; n < 4; ++n) {
      bf16x8 vb = *(const bf16x8*)&vts[n * 16 + fr][kk + fg * 8];
      oa[n] = __builtin_amdgcn_mfma_f32_16x16x32_bf16(pa, vb, oa[n], 0, 0, 0);
    }
  }
  #pragma unroll
  for (int n = 0; n < 4; ++n)
    #pragma unroll
    for (int i = 0; i < 4; ++i) {
      const int row = w * 16 + fg * 4 + i, col = n * 16 + fr;
      y[(size_t)(b * 64 + row) * 1024 + h * 64 + col] = f2bf(oa[n][i]);
    }
}

// ---------------- final LayerNorm ----------------
__global__ void __launch_bounds__(256)
ln_kernel(const float* __restrict__ x, const float* __restrict__ g,
          const float* __restrict__ bb, u16* __restrict__ xn) {
  __shared__ float sred[8];
  const int tok = blockIdx.x;
  const int t = threadIdx.x;
  const float4 v = ((const float4*)(x + (size_t)tok * 1024))[t];
  float s  = v.x + v.y + v.z + v.w;
  float ss = v.x * v.x + v.y * v.y + v.z * v.z + v.w * v.w;
  #pragma unroll
  for (int o = 32; o > 0; o >>= 1) {
    s  += __shfl_xor(s, o);
    ss += __shfl_xor(ss, o);
  }
  const int w = t >> 6;
  if ((t & 63) == 0) { sred[w] = s; sred[4 + w] = ss; }
  __syncthreads();
  s  = sred[0] + sred[1] + sred[2] + sred[3];
  ss = sred[4] + sred[5] + sred[6] + sred[7];
  const float mu = s * (1.0f / 1024.0f);
  const float var = ss * (1.0f / 1024.0f) - mu * mu;
  const float rs = rsqrtf(var + 1e-5f);
  const float4 gg = ((const float4*)g)[t];
  const float4 b4 = ((const float4*)bb)[t];
  u16* o = xn + (size_t)tok * 1024 + t * 4;
  o[0] = f2bf((v.x - mu) * rs * gg.x + b4.x);
  o[1] = f2bf((v.y - mu) * rs * gg.y + b4.y);
  o[2] = f2bf((v.z - mu) * rs * gg.z + b4.z);
  o[3] = f2bf((v.w - mu) * rs * gg.w + b4.w);
}

// ---------------- host ----------------
extern "C" void kernel_launch(void* const* d_in, const int* in_sizes, int n_in,
                              void* d_out, int out_size, void* d_ws, size_t ws_size,
                              hipStream_t stream) {
  const int*   idx     = (const int*)  d_in[0];
  const float* tok_emb = (const float*)d_in[1];
  const float* pos_emb = (const float*)d_in[2];
  const float* wqkv    = (const float*)d_in[3];
  const float* bqkv    = (const float*)d_in[4];
  const float* wo      = (const float*)d_in[5];
  const float* bo      = (const float*)d_in[6];
  const float* w1      = (const float*)d_in[7];
  const float* b1      = (const float*)d_in[8];
  const float* w2      = (const float*)d_in[9];
  const float* b2      = (const float*)d_in[10];
  const float* ln_g    = (const float*)d_in[11];
  const float* ln_b    = (const float*)d_in[12];
  const float* out_w   = (const float*)d_in[13];
  const float* out_b   = (const float*)d_in[14];

  char* p = (char*)d_ws;
  auto take = [&](size_t n) { char* r = p; p += (n + 255) & ~(size_t)255; return r; };
  u16*   wqkv_t = (u16*)  take((size_t)1024 * 3072 * 2);
  u16*   wo_t   = (u16*)  take((size_t)1024 * 1024 * 2);
  u16*   w1_t   = (u16*)  take((size_t)1024 * 4096 * 2);
  u16*   w2_t   = (u16*)  take((size_t)4096 * 1024 * 2);
  u16*   wout_t = (u16*)  take((size_t)1024 * 1024 * 2);
  float* xf     = (float*)take((size_t)MT * 1024 * 4);
  u16*   xb     = (u16*)  take((size_t)MT * 1024 * 2);
  u16*   yb     = (u16*)  take((size_t)MT * 1024 * 2);
  u16*   big    = (u16*)  take((size_t)MT * 4096 * 2);

  const dim3 tb(32, 8);
  embed_kernel<<<MT, 256, 0, stream>>>(idx, tok_emb, pos_emb, xf, xb);

  for (int l = 0; l < 12; ++l) {
    transpose_cvt<<<dim3(3072 / 32, 1024 / 32), tb, 0, stream>>>(
        wqkv + (size_t)l * 1024 * 3072, wqkv_t, 1024, 3072);
    transpose_cvt<<<dim3(1024 / 32, 1024 / 32), tb, 0, stream>>>(
        wo + (size_t)l * 1024 * 1024, wo_t, 1024, 1024);
    transpose_cvt<<<dim3(4096 / 32, 1024 / 32), tb, 0, stream>>>(
        w1 + (size_t)l * 1024 * 4096, w1_t, 1024, 4096);
    transpose_cvt<<<dim3(1024 / 32, 4096 / 32), tb, 0, stream>>>(
        w2 + (size_t)l * 4096 * 1024, w2_t, 4096, 1024);

    gemm128<0><<<(MT / 128) * (3072 / 128), 256, 0, stream>>>(
        xb, wqkv_t, bqkv + (size_t)l * 3072,
        nullptr, big, nullptr, MT, 3072, 1024, 3072 / 128);
    attn_kernel<<<dim3(16, 256), 256, 0, stream>>>(big, yb);
    gemm128<2><<<(MT / 128) * (1024 / 128), 256, 0, stream>>>(
        yb, wo_t, bo + (size_t)l * 1024,
        xf, xb, nullptr, MT, 1024, 1024, 1024 / 128);
    gemm128<1><<<(MT / 128) * (4096 / 128), 256, 0, stream>>>(
        xb, w1_t, b1 + (size_t)l * 4096,
        nullptr, big, nullptr, MT, 4096, 1024, 4096 / 128);
    gemm128<2><<<(MT / 128) * (1024 / 128), 256, 0, stream>>>(
        big, w2_t, b2 + (size_t)l * 1024,
        xf, xb, nullptr, MT, 1024, 4096, 1024 / 128);
  }

  transpose_cvt<<<dim3(1024 / 32, 1024 / 32), tb, 0, stream>>>(out_w, wout_t, 1024, 1024);
  ln_kernel<<<MT, 256, 0, stream>>>(xf, ln_g, ln_b, yb);
  gemm128<3><<<(MT / 128) * (1024 / 128), 256, 0, stream>>>(
      yb, wout_t, out_b, nullptr, nullptr, (float*)d_out, MT, 1024, 1024, 1024 / 128);
}

// Round 11
// 7401.048 us; speedup vs baseline: 1.1159x; 1.1159x over previous
//
#include <hip/hip_runtime.h>
#include <stdint.h>

typedef unsigned short u16;
typedef __bf16 bf16x8 __attribute__((ext_vector_type(8)));
typedef float f32x4 __attribute__((ext_vector_type(4)));

#define MT 16384   // BATCH*SEQ tokens

__device__ __forceinline__ u16 f2bf(float f) {
  union { float f; unsigned u; } x; x.f = f;
  unsigned r = x.u + 0x7fffu + ((x.u >> 16) & 1u);   // RNE
  return (u16)(r >> 16);
}

#pragma clang diagnostic push
#pragma clang diagnostic ignored "-Waddress-space-conversion"
typedef __attribute__((address_space(1))) unsigned as1u;
typedef __attribute__((address_space(3))) unsigned as3u;
// async global->LDS, 16B per lane; lbase must be wave-uniform (HW adds lane*16)
__device__ __forceinline__ void stage16(const u16* g, const u16* lbase) {
  __builtin_amdgcn_global_load_lds((as1u*)g, (as3u*)lbase, 16, 0, 0);
}
#pragma clang diagnostic pop

// ---------------- weight transpose + f32->bf16 convert ----------------
__global__ void __launch_bounds__(256)
transpose_cvt(const float* __restrict__ in, u16* __restrict__ out, int K, int N) {
  __shared__ float tile[32][33];
  const int k0 = blockIdx.y * 32, n0 = blockIdx.x * 32;
  const int tx = threadIdx.x, ty = threadIdx.y;   // block (32,8)
  #pragma unroll
  for (int r = 0; r < 32; r += 8)
    tile[ty + r][tx] = in[(size_t)(k0 + ty + r) * N + n0 + tx];
  __syncthreads();
  #pragma unroll
  for (int r = 0; r < 32; r += 8)
    out[(size_t)(n0 + ty + r) * K + k0 + tx] = f2bf(tile[tx][ty + r]);
}

// ---------------- embedding: x = tok_emb[idx] + pos_emb ----------------
__global__ void __launch_bounds__(256)
embed_kernel(const int* __restrict__ idx, const float* __restrict__ tok,
             const float* __restrict__ pos, float* __restrict__ x,
             u16* __restrict__ xb) {
  const int tk = blockIdx.x;
  const int s = tk & 63;
  const int id = idx[tk];
  const int t = threadIdx.x;
  float4 a = ((const float4*)(tok + (size_t)id * 1024))[t];
  float4 p = ((const float4*)(pos + (size_t)s * 1024))[t];
  float4 r; r.x = a.x + p.x; r.y = a.y + p.y; r.z = a.z + p.z; r.w = a.w + p.w;
  ((float4*)(x + (size_t)tk * 1024))[t] = r;
  u16* o = xb + (size_t)tk * 1024 + t * 4;
  o[0] = f2bf(r.x); o[1] = f2bf(r.y); o[2] = f2bf(r.z); o[3] = f2bf(r.w);
}

// ------------- 256x128 pipelined GEMM: C = A[M][K](bf16) @ Bt[N][K]^T + bias -------------
// 8 waves (4Mx2N), BK=32. A TRIPLE-buffered (3x16KB, staged 2 steps ahead: HBM
// cover), B DOUBLE-buffered (2x8KB, 1 step ahead: L2-hot weights). 64KB LDS ->
// 2 blocks/CU = 16 waves/CU (R10 lesson: 48KBx3=147KB didn't fit; usable LDS
// >= 131072 per R4). Per-step issue order: B(u+1), A(u+2)x2 -> queue at top of
// step u = [A(u)x2, B(u), A(u+1)x2]; vmcnt(2) publishes A(u)+B(u), leaves
// A(u+1) in flight. Raw s_barrier + sched_barrier(0) fences ds_read hoisting.
// Packed-pair 0-conflict swizzle identical to R9 (proven).
// EPI 0: out bf16 | 1: gelu->bf16 | 2: +res(f32), write f32+bf16 | 3: out f32
template<int EPI>
__global__ void __launch_bounds__(512, 4)
gemm256x128(const u16* __restrict__ A, const u16* __restrict__ Bt,
            const float* __restrict__ bias, float* __restrict__ resf,
            u16* __restrict__ outb, float* __restrict__ outf,
            int M, int N, int K, int gn) {
  __shared__ __align__(16) u16 lA[3][8192];   // 256 rows x 32 k bf16 per buffer
  __shared__ __align__(16) u16 lB[2][4096];   // 128 rows x 32 k bf16 per buffer
  const int t = threadIdx.x;
  const int lane = t & 63, w = t >> 6;        // 8 waves: (wr,wc) 4x2
  const int wr = w >> 1, wc = w & 1;
  const int fr = lane & 15, fg = lane >> 4;

  // XCD swizzle (grid %8==0) + tn-fastest decomposition for A-panel L2 reuse
  const int nwg = gridDim.x;
  const int bid = blockIdx.x;
  const int s = (bid & 7) * (nwg >> 3) + (bid >> 3);
  const int tn = s % gn, tm = s / gn;
  const int m0 = tm * 256, n0 = tn * 128;

  // staging source mapping (inverse of packed-pair swizzle); chunk = 16 rows = 1KB
  const int rin = ((lane >> 3) << 1) + ((lane >> 2) & 1);   // row within chunk
  const int fgl = (lane & 3) ^ ((lane >> 3) & 3);           // logical k-granule
  // A: 16 chunks, wave w stages chunks w*2, w*2+1. B: 8 chunks, wave w stages chunk w.
  const u16* gA0 = A  + (size_t)(m0 + (w * 2 + 0) * 16 + rin) * K + fgl * 8;
  const u16* gA1 = A  + (size_t)(m0 + (w * 2 + 1) * 16 + rin) * K + fgl * 8;
  const u16* gB  = Bt + (size_t)(n0 + w * 16 + rin) * K + fgl * 8;

  // LDS read offsets (u16 units): chunk*512 + line*64 + sub8
  const int sub8 = ((fr & 1) * 4 + (fg ^ ((fr >> 1) & 3))) * 8;
  const int ar = wr * 2048 + (fr >> 1) * 64 + sub8;   // + m*512
  const int br = wc * 2048 + (fr >> 1) * 64 + sub8;   // + n*512

  f32x4 acc[4][4] = {};
  const int NT = K >> 5;

  // prologue ledger: [B(0), A(0)x2, A(1)x2]
  stage16(gB,        &lB[0][w * 512]);
  stage16(gA0,       &lA[0][(w * 2 + 0) * 512]);
  stage16(gA1,       &lA[0][(w * 2 + 1) * 512]);
  stage16(gA0 + 32,  &lA[1][(w * 2 + 0) * 512]);
  stage16(gA1 + 32,  &lA[1][(w * 2 + 1) * 512]);

  int bufA = 0, bufB = 0;
  for (int u = 0; u < NT; ++u) {
    asm volatile("s_waitcnt vmcnt(2)" ::: "memory");  // publish A(u), B(u); A(u+1) flies
    __builtin_amdgcn_s_barrier();
    __builtin_amdgcn_sched_barrier(0);                // no ds_read hoists above

    int kt1 = u + 1; if (kt1 >= NT) kt1 -= NT;        // wrap keeps ledger uniform
    int kt2 = u + 2; if (kt2 >= NT) kt2 -= NT;
    const int ko1 = kt1 << 5, ko2 = kt2 << 5;
    const int bA2 = (bufA + 2 >= 3) ? bufA - 1 : bufA + 2;
    stage16(gB  + ko1, &lB[bufB ^ 1][w * 512]);       // B(u+1)
    stage16(gA0 + ko2, &lA[bA2][(w * 2 + 0) * 512]);  // A(u+2)
    stage16(gA1 + ko2, &lA[bA2][(w * 2 + 1) * 512]);

    bf16x8 af[4], bv[4];
    #pragma unroll
    for (int m = 0; m < 4; ++m) af[m] = *(const bf16x8*)&lA[bufA][ar + m * 512];
    #pragma unroll
    for (int n = 0; n < 4; ++n) bv[n] = *(const bf16x8*)&lB[bufB][br + n * 512];
    #pragma unroll
    for (int m = 0; m < 4; ++m)
      #pragma unroll
      for (int n = 0; n < 4; ++n)
        acc[m][n] = __builtin_amdgcn_mfma_f32_16x16x32_bf16(af[m], bv[n], acc[m][n], 0, 0, 0);

    bufA = (bufA == 2) ? 0 : bufA + 1;
    bufB ^= 1;
  }
  asm volatile("s_waitcnt vmcnt(0)" ::: "memory");    // drain wrap stages

  #pragma unroll
  for (int m = 0; m < 4; ++m) {
    const int row = m0 + wr * 64 + m * 16 + fg * 4;
    #pragma unroll
    for (int n = 0; n < 4; ++n) {
      const int col = n0 + wc * 64 + n * 16 + fr;
      const float bc = bias[col];
      #pragma unroll
      for (int i = 0; i < 4; ++i) {
        const size_t off = (size_t)(row + i) * N + col;
        float v = acc[m][n][i] + bc;
        if constexpr (EPI == 0) {
          outb[off] = f2bf(v);
        } else if constexpr (EPI == 1) {
          v = 0.5f * v * (1.0f + erff(v * 0.70710678118654752f));
          outb[off] = f2bf(v);
        } else if constexpr (EPI == 2) {
          v += resf[off];
          resf[off] = v;
          outb[off] = f2bf(v);
        } else {
          outf[off] = v;
        }
      }
    }
  }
}

// ---------------- attention (one block per (b,h)) ----------------
__global__ void __launch_bounds__(256)
attn_kernel(const u16* __restrict__ qkv, u16* __restrict__ y) {
  __shared__ __align__(16) u16 qs[64][72];    // Q; reused as P (bf16)
  __shared__ __align__(16) u16 ks[64][72];
  __shared__ __align__(16) u16 vts[64][72];   // V transposed: [dh][key]
  __shared__ __align__(16) float S[64][68];   // [query][key] f32
  __shared__ float red[4][64];

  const int h = blockIdx.x, b = blockIdx.y;
  const int t = threadIdx.x;
  const int lane = t & 63, w = t >> 6;
  const int fr = lane & 15, fg = lane >> 4;

  #pragma unroll
  for (int it = 0; it < 2; ++it) {
    const int id = t + it * 256;           // 0..511
    const int row = id >> 3, seg = id & 7;
    const size_t gq = (size_t)(b * 64 + row) * 3072 + h * 64 + seg * 8;
    *(uint4*)&qs[row][seg * 8] = *(const uint4*)&qkv[gq];
    *(uint4*)&ks[row][seg * 8] = *(const uint4*)&qkv[gq + 1024];
  }
  {
    const int d = t & 63;
    #pragma unroll
    for (int it = 0; it < 16; ++it) {
      const int s = (t >> 6) + it * 4;
      vts[d][s] = qkv[(size_t)(b * 64 + s) * 3072 + 2048 + h * 64 + d];
    }
  }
  __syncthreads();

  f32x4 sa[4] = {};
  #pragma unroll
  for (int kk = 0; kk < 64; kk += 32) {
    bf16x8 qa = *(const bf16x8*)&qs[w * 16 + fr][kk + fg * 8];
    #pragma unroll
    for (int n = 0; n < 4; ++n) {
      bf16x8 kb = *(const bf16x8*)&ks[n * 16 + fr][kk + fg * 8];
      sa[n] = __builtin_amdgcn_mfma_f32_16x16x32_bf16(qa, kb, sa[n], 0, 0, 0);
    }
  }
  #pragma unroll
  for (int n = 0; n < 4; ++n)
    #pragma unroll
    for (int i = 0; i < 4; ++i) {
      const int row = w * 16 + fg * 4 + i, col = n * 16 + fr;
      S[row][col] = (row >= col) ? sa[n][i] * 0.03125f : -1e30f;
    }
  __syncthreads();

  const int c = t & 63, q4 = t >> 6;
  float mx = -1e30f;
  float e[16];
  #pragma unroll
  for (int i = 0; i < 16; ++i) mx = fmaxf(mx, S[q4 * 16 + i][c]);
  red[q4][c] = mx;
  __syncthreads();
  mx = fmaxf(fmaxf(red[0][c], red[1][c]), fmaxf(red[2][c], red[3][c]));
  float sum = 0.f;
  #pragma unroll
  for (int i = 0; i < 16; ++i) { e[i] = __expf(S[q4 * 16 + i][c] - mx); sum += e[i]; }
  __syncthreads();
  red[q4][c] = sum;
  __syncthreads();
  sum = red[0][c] + red[1][c] + red[2][c] + red[3][c];
  const float inv = 1.0f / sum;
  u16 (*P)[72] = qs;
  #pragma unroll
  for (int i = 0; i < 16; ++i)
    P[q4 * 16 + i][c] = f2bf(e[i] * inv);
  __syncthreads();

  f32x4 oa[4] = {};
  #pragma unroll
  for (int kk = 0; kk < 64; kk += 32) {
    bf16x8 pa = *(const bf16x8*)&P[w * 16 + fr][kk + fg * 8];
    #pragma unroll
    for (int n = 0; n < 4; ++n) {
      bf16x8 vb = *(const bf16x8*)&vts[n * 16 + fr][kk + fg * 8];
      oa[n] = __builtin_amdgcn_mfma_f32_16x16x32_bf16(pa, vb, oa[n], 0, 0, 0);
    }
  }
  #pragma unroll
  for (int n = 0; n < 4; ++n)
    #pragma unroll
    for (int i = 0; i < 4; ++i) {
      const int row = w * 16 + fg * 4 + i, col = n * 16 + fr;
      y[(size_t)(b * 64 + row) * 1024 + h * 64 + col] = f2bf(oa[n][i]);
    }
}

// ---------------- final LayerNorm ----------------
__global__ void __launch_bounds__(256)
ln_kernel(const float* __restrict__ x, const float* __restrict__ g,
          const float* __restrict__ bb, u16* __restrict__ xn) {
  __shared__ float sred[8];
  const int tok = blockIdx.x;
  const int t = threadIdx.x;
  const float4 v = ((const float4*)(x + (size_t)tok * 1024))[t];
  float s  = v.x + v.y + v.z + v.w;
  float ss = v.x * v.x + v.y * v.y + v.z * v.z + v.w * v.w;
  #pragma unroll
  for (int o = 32; o > 0; o >>= 1) {
    s  += __shfl_xor(s, o);
    ss += __shfl_xor(ss, o);
  }
  const int w = t >> 6;
  if ((t & 63) == 0) { sred[w] = s; sred[4 + w] = ss; }
  __syncthreads();
  s  = sred[0] + sred[1] + sred[2] + sred[3];
  ss = sred[4] + sred[5] + sred[6] + sred[7];
  const float mu = s * (1.0f / 1024.0f);
  const float var = ss * (1.0f / 1024.0f) - mu * mu;
  const float rs = rsqrtf(var + 1e-5f);
  const float4 gg = ((const float4*)g)[t];
  const float4 b4 = ((const float4*)bb)[t];
  u16* o = xn + (size_t)tok * 1024 + t * 4;
  o[0] = f2bf((v.x - mu) * rs * gg.x + b4.x);
  o[1] = f2bf((v.y - mu) * rs * gg.y + b4.y);
  o[2] = f2bf((v.z - mu) * rs * gg.z + b4.z);
  o[3] = f2bf((v.w - mu) * rs * gg.w + b4.w);
}

// ---------------- host ----------------
extern "C" void kernel_launch(void* const* d_in, const int* in_sizes, int n_in,
                              void* d_out, int out_size, void* d_ws, size_t ws_size,
                              hipStream_t stream) {
  const int*   idx     = (const int*)  d_in[0];
  const float* tok_emb = (const float*)d_in[1];
  const float* pos_emb = (const float*)d_in[2];
  const float* wqkv    = (const float*)d_in[3];
  const float* bqkv    = (const float*)d_in[4];
  const float* wo      = (const float*)d_in[5];
  const float* bo      = (const float*)d_in[6];
  const float* w1      = (const float*)d_in[7];
  const float* b1      = (const float*)d_in[8];
  const float* w2      = (const float*)d_in[9];
  const float* b2      = (const float*)d_in[10];
  const float* ln_g    = (const float*)d_in[11];
  const float* ln_b    = (const float*)d_in[12];
  const float* out_w   = (const float*)d_in[13];
  const float* out_b   = (const float*)d_in[14];

  char* p = (char*)d_ws;
  auto take = [&](size_t n) { char* r = p; p += (n + 255) & ~(size_t)255; return r; };
  u16*   wqkv_t = (u16*)  take((size_t)1024 * 3072 * 2);
  u16*   wo_t   = (u16*)  take((size_t)1024 * 1024 * 2);
  u16*   w1_t   = (u16*)  take((size_t)1024 * 4096 * 2);
  u16*   w2_t   = (u16*)  take((size_t)4096 * 1024 * 2);
  u16*   wout_t = (u16*)  take((size_t)1024 * 1024 * 2);
  float* xf     = (float*)take((size_t)MT * 1024 * 4);
  u16*   xb     = (u16*)  take((size_t)MT * 1024 * 2);
  u16*   yb     = (u16*)  take((size_t)MT * 1024 * 2);
  u16*   big    = (u16*)  take((size_t)MT * 4096 * 2);

  const dim3 tb(32, 8);
  embed_kernel<<<MT, 256, 0, stream>>>(idx, tok_emb, pos_emb, xf, xb);

  for (int l = 0; l < 12; ++l) {
    transpose_cvt<<<dim3(3072 / 32, 1024 / 32), tb, 0, stream>>>(
        wqkv + (size_t)l * 1024 * 3072, wqkv_t, 1024, 3072);
    transpose_cvt<<<dim3(1024 / 32, 1024 / 32), tb, 0, stream>>>(
        wo + (size_t)l * 1024 * 1024, wo_t, 1024, 1024);
    transpose_cvt<<<dim3(4096 / 32, 1024 / 32), tb, 0, stream>>>(
        w1 + (size_t)l * 1024 * 4096, w1_t, 1024, 4096);
    transpose_cvt<<<dim3(1024 / 32, 4096 / 32), tb, 0, stream>>>(
        w2 + (size_t)l * 4096 * 1024, w2_t, 4096, 1024);

    gemm256x128<0><<<(MT / 256) * (3072 / 128), 512, 0, stream>>>(
        xb, wqkv_t, bqkv + (size_t)l * 3072,
        nullptr, big, nullptr, MT, 3072, 1024, 3072 / 128);
    attn_kernel<<<dim3(16, 256), 256, 0, stream>>>(big, yb);
    gemm256x128<2><<<(MT / 256) * (1024 / 128), 512, 0, stream>>>(
        yb, wo_t, bo + (size_t)l * 1024,
        xf, xb, nullptr, MT, 1024, 1024, 1024 / 128);
    gemm256x128<1><<<(MT / 256) * (4096 / 128), 512, 0, stream>>>(
        xb, w1_t, b1 + (size_t)l * 4096,
        nullptr, big, nullptr, MT, 4096, 1024, 4096 / 128);
    gemm256x128<2><<<(MT / 256) * (1024 / 128), 512, 0, stream>>>(
        big, w2_t, b2 + (size_t)l * 1024,
        xf, xb, nullptr, MT, 1024, 4096, 1024 / 128);
  }

  transpose_cvt<<<dim3(1024 / 32, 1024 / 32), tb, 0, stream>>>(out_w, wout_t, 1024, 1024);
  ln_kernel<<<MT, 256, 0, stream>>>(xf, ln_g, ln_b, yb);
  gemm256x128<3><<<(MT / 256) * (1024 / 128), 512, 0, stream>>>(
      yb, wout_t, out_b, nullptr, nullptr, (float*)d_out, MT, 1024, 1024, 1024 / 128);
}

// Round 12
// 6630.403 us; speedup vs baseline: 1.2456x; 1.1162x over previous
//
#include <hip/hip_runtime.h>
#include <stdint.h>

typedef unsigned short u16;
typedef __bf16 bf16x8 __attribute__((ext_vector_type(8)));
typedef float f32x4 __attribute__((ext_vector_type(4)));

#define MT 16384   // BATCH*SEQ tokens

__device__ __forceinline__ u16 f2bf(float f) {
  union { float f; unsigned u; } x; x.f = f;
  unsigned r = x.u + 0x7fffu + ((x.u >> 16) & 1u);   // RNE
  return (u16)(r >> 16);
}
__device__ __forceinline__ float bf2f(u16 b) {
  union { float f; unsigned u; } x; x.u = ((unsigned)b) << 16;
  return x.f;
}

#pragma clang diagnostic push
#pragma clang diagnostic ignored "-Waddress-space-conversion"
typedef __attribute__((address_space(1))) unsigned as1u;
typedef __attribute__((address_space(3))) unsigned as3u;
// async global->LDS, 16B per lane; lbase must be wave-uniform (HW adds lane*16)
__device__ __forceinline__ void stage16(const u16* g, const u16* lbase) {
  __builtin_amdgcn_global_load_lds((as1u*)g, (as3u*)lbase, 16, 0, 0);
}
#pragma clang diagnostic pop

// ---------------- weight transpose + f32->bf16 convert ----------------
__global__ void __launch_bounds__(256)
transpose_cvt(const float* __restrict__ in, u16* __restrict__ out, int K, int N) {
  __shared__ float tile[32][33];
  const int k0 = blockIdx.y * 32, n0 = blockIdx.x * 32;
  const int tx = threadIdx.x, ty = threadIdx.y;   // block (32,8)
  #pragma unroll
  for (int r = 0; r < 32; r += 8)
    tile[ty + r][tx] = in[(size_t)(k0 + ty + r) * N + n0 + tx];
  __syncthreads();
  #pragma unroll
  for (int r = 0; r < 32; r += 8)
    out[(size_t)(n0 + ty + r) * K + k0 + tx] = f2bf(tile[tx][ty + r]);
}

// ---------------- embedding: xb = bf16(tok_emb[idx] + pos_emb) ----------------
__global__ void __launch_bounds__(256)
embed_kernel(const int* __restrict__ idx, const float* __restrict__ tok,
             const float* __restrict__ pos, u16* __restrict__ xb) {
  const int tk = blockIdx.x;
  const int s = tk & 63;
  const int id = idx[tk];
  const int t = threadIdx.x;
  float4 a = ((const float4*)(tok + (size_t)id * 1024))[t];
  float4 p = ((const float4*)(pos + (size_t)s * 1024))[t];
  u16* o = xb + (size_t)tk * 1024 + t * 4;
  o[0] = f2bf(a.x + p.x); o[1] = f2bf(a.y + p.y);
  o[2] = f2bf(a.z + p.z); o[3] = f2bf(a.w + p.w);
}

// ------------- 256x256 GEMM (R4 verbatim): C = A @ Bt^T + bias -------------
// 8 waves (2Mx4N), BK=64, double-buffered 128KiB LDS, XOR-swizzled reads,
// inverse-swizzled global_load_lds sources, XCD-aware block swizzle.
// EPI 0: out bf16 | 1: gelu->bf16 | 2: res-bf16 in-place (+= then write) | 3: out f32
template<int EPI>
__global__ void __launch_bounds__(512, 2)
gemm256(const u16* __restrict__ A, const u16* __restrict__ Bt,
        const float* __restrict__ bias, u16* __restrict__ resb,
        u16* __restrict__ outb, float* __restrict__ outf,
        int M, int N, int K, int gn) {
  __shared__ __align__(16) u16 lds[2][2][16384];   // [buf][A|B][256*64]
  const int t = threadIdx.x;
  const int lane = t & 63, w = t >> 6;
  const int wr = w >> 2, wc = w & 3;
  const int fr = lane & 15, fg = lane >> 4;

  const int nwg = gridDim.x;
  const int bid = blockIdx.x;
  const int s = (bid & 7) * (nwg >> 3) + (bid >> 3);
  const int tn = s % gn, tm = s / gn;
  const int m0 = tm * 256, n0 = tn * 256;

  const int srow = w * 8 + (lane >> 3);
  const int sg = (lane & 7) ^ (lane >> 3);
  const u16* gA[4]; const u16* gB[4];
  #pragma unroll
  for (int c = 0; c < 4; ++c) {
    gA[c] = A  + (size_t)(m0 + c * 64 + srow) * K + sg * 8;
    gB[c] = Bt + (size_t)(n0 + c * 64 + srow) * K + sg * 8;
  }
  const int lofs = w * 512;

  f32x4 acc[8][4] = {};
  const int NT = K >> 6;

  #pragma unroll
  for (int c = 0; c < 4; ++c) {
    stage16(gA[c], &lds[0][0][lofs + c * 4096]);
    stage16(gB[c], &lds[0][1][lofs + c * 4096]);
  }
  __syncthreads();

  int cur = 0;
  for (int kt = 0; kt < NT; ++kt) {
    if (kt + 1 < NT) {
      const int koff = (kt + 1) << 6;
      #pragma unroll
      for (int c = 0; c < 4; ++c) {
        stage16(gA[c] + koff, &lds[cur ^ 1][0][lofs + c * 4096]);
        stage16(gB[c] + koff, &lds[cur ^ 1][1][lofs + c * 4096]);
      }
    }
    #pragma unroll
    for (int h = 0; h < 2; ++h) {
      bf16x8 af[8], bv[4];
      #pragma unroll
      for (int m = 0; m < 8; ++m) {
        const int row = wr * 128 + m * 16 + fr;
        const int g = (fg + h * 4) ^ (fr & 7);
        af[m] = *(const bf16x8*)&lds[cur][0][row * 64 + g * 8];
      }
      #pragma unroll
      for (int n = 0; n < 4; ++n) {
        const int row = wc * 64 + n * 16 + fr;
        const int g = (fg + h * 4) ^ (fr & 7);
        bv[n] = *(const bf16x8*)&lds[cur][1][row * 64 + g * 8];
      }
      #pragma unroll
      for (int m = 0; m < 8; ++m)
        #pragma unroll
        for (int n = 0; n < 4; ++n)
          acc[m][n] = __builtin_amdgcn_mfma_f32_16x16x32_bf16(af[m], bv[n], acc[m][n], 0, 0, 0);
    }
    __syncthreads();
    cur ^= 1;
  }

  #pragma unroll
  for (int m = 0; m < 8; ++m) {
    const int row = m0 + wr * 128 + m * 16 + fg * 4;
    #pragma unroll
    for (int n = 0; n < 4; ++n) {
      const int col = n0 + wc * 64 + n * 16 + fr;
      const float bc = bias[col];
      #pragma unroll
      for (int i = 0; i < 4; ++i) {
        const size_t off = (size_t)(row + i) * N + col;
        float v = acc[m][n][i] + bc;
        if constexpr (EPI == 0) {
          outb[off] = f2bf(v);
        } else if constexpr (EPI == 1) {
          v = 0.5f * v * (1.0f + erff(v * 0.70710678118654752f));
          outb[off] = f2bf(v);
        } else if constexpr (EPI == 2) {
          v += bf2f(resb[off]);
          resb[off] = f2bf(v);
        } else {
          outf[off] = v;
        }
      }
    }
  }
}

// ---------------- 128x128 GEMM (R9 verbatim, W2 only) ----------------
template<int EPI>
__global__ void __launch_bounds__(256, 3)
gemm128(const u16* __restrict__ A, const u16* __restrict__ Bt,
        const float* __restrict__ bias, u16* __restrict__ resb,
        u16* __restrict__ outb, float* __restrict__ outf,
        int M, int N, int K, int gn) {
  __shared__ __align__(16) u16 lA[2][4096];   // 128 rows x 32 k bf16 per buffer
  __shared__ __align__(16) u16 lB[2][4096];
  const int t = threadIdx.x;
  const int lane = t & 63, w = t >> 6;
  const int wr = w >> 1, wc = w & 1;
  const int fr = lane & 15, fg = lane >> 4;

  const int nwg = gridDim.x;
  const int bid = blockIdx.x;
  const int s = (bid & 7) * (nwg >> 3) + (bid >> 3);
  const int tn = s % gn, tm = s / gn;
  const int m0 = tm * 128, n0 = tn * 128;

  const int rin = ((lane >> 3) << 1) + ((lane >> 2) & 1);
  const int fgl = (lane & 3) ^ ((lane >> 3) & 3);
  const u16* gA[2]; const u16* gB[2];
  #pragma unroll
  for (int i = 0; i < 2; ++i) {
    gA[i] = A  + (size_t)(m0 + (w * 2 + i) * 16 + rin) * K + fgl * 8;
    gB[i] = Bt + (size_t)(n0 + (w * 2 + i) * 16 + rin) * K + fgl * 8;
  }

  const int sub8 = ((fr & 1) * 4 + (fg ^ ((fr >> 1) & 3))) * 8;
  const int ar = wr * 2048 + (fr >> 1) * 64 + sub8;
  const int br = wc * 2048 + (fr >> 1) * 64 + sub8;

  f32x4 acc[4][4] = {};
  const int NT = K >> 5;

  #pragma unroll
  for (int i = 0; i < 2; ++i) {
    stage16(gA[i], &lA[0][(w * 2 + i) * 512]);
    stage16(gB[i], &lB[0][(w * 2 + i) * 512]);
  }
  __syncthreads();

  int cur = 0;
  for (int kt = 0; kt < NT; ++kt) {
    if (kt + 1 < NT) {
      const int ko = (kt + 1) << 5;
      #pragma unroll
      for (int i = 0; i < 2; ++i) {
        stage16(gA[i] + ko, &lA[cur ^ 1][(w * 2 + i) * 512]);
        stage16(gB[i] + ko, &lB[cur ^ 1][(w * 2 + i) * 512]);
      }
    }
    bf16x8 af[4], bv[4];
    #pragma unroll
    for (int m = 0; m < 4; ++m) af[m] = *(const bf16x8*)&lA[cur][ar + m * 512];
    #pragma unroll
    for (int n = 0; n < 4; ++n) bv[n] = *(const bf16x8*)&lB[cur][br + n * 512];
    #pragma unroll
    for (int m = 0; m < 4; ++m)
      #pragma unroll
      for (int n = 0; n < 4; ++n)
        acc[m][n] = __builtin_amdgcn_mfma_f32_16x16x32_bf16(af[m], bv[n], acc[m][n], 0, 0, 0);
    __syncthreads();
    cur ^= 1;
  }

  #pragma unroll
  for (int m = 0; m < 4; ++m) {
    const int row = m0 + wr * 64 + m * 16 + fg * 4;
    #pragma unroll
    for (int n = 0; n < 4; ++n) {
      const int col = n0 + wc * 64 + n * 16 + fr;
      const float bc = bias[col];
      #pragma unroll
      for (int i = 0; i < 4; ++i) {
        const size_t off = (size_t)(row + i) * N + col;
        float v = acc[m][n][i] + bc;
        if constexpr (EPI == 0) {
          outb[off] = f2bf(v);
        } else if constexpr (EPI == 1) {
          v = 0.5f * v * (1.0f + erff(v * 0.70710678118654752f));
          outb[off] = f2bf(v);
        } else if constexpr (EPI == 2) {
          v += bf2f(resb[off]);
          resb[off] = f2bf(v);
        } else {
          outf[off] = v;
        }
      }
    }
  }
}

// ---------------- attention (one block per (b,h)) ----------------
__global__ void __launch_bounds__(256)
attn_kernel(const u16* __restrict__ qkv, u16* __restrict__ y) {
  __shared__ __align__(16) u16 qs[64][72];    // Q; reused as P (bf16)
  __shared__ __align__(16) u16 ks[64][72];
  __shared__ __align__(16) u16 vts[64][72];   // V transposed: [dh][key]
  __shared__ __align__(16) float S[64][68];   // [query][key] f32
  __shared__ float red[4][64];

  const int h = blockIdx.x, b = blockIdx.y;
  const int t = threadIdx.x;
  const int lane = t & 63, w = t >> 6;
  const int fr = lane & 15, fg = lane >> 4;

  #pragma unroll
  for (int it = 0; it < 2; ++it) {
    const int id = t + it * 256;           // 0..511
    const int row = id >> 3, seg = id & 7;
    const size_t gq = (size_t)(b * 64 + row) * 3072 + h * 64 + seg * 8;
    *(uint4*)&qs[row][seg * 8] = *(const uint4*)&qkv[gq];
    *(uint4*)&ks[row][seg * 8] = *(const uint4*)&qkv[gq + 1024];
  }
  {
    const int d = t & 63;
    #pragma unroll
    for (int it = 0; it < 16; ++it) {
      const int s = (t >> 6) + it * 4;
      vts[d][s] = qkv[(size_t)(b * 64 + s) * 3072 + 2048 + h * 64 + d];
    }
  }
  __syncthreads();

  f32x4 sa[4] = {};
  #pragma unroll
  for (int kk = 0; kk < 64; kk += 32) {
    bf16x8 qa = *(const bf16x8*)&qs[w * 16 + fr][kk + fg * 8];
    #pragma unroll
    for (int n = 0; n < 4; ++n) {
      bf16x8 kb = *(const bf16x8*)&ks[n * 16 + fr][kk + fg * 8];
      sa[n] = __builtin_amdgcn_mfma_f32_16x16x32_bf16(qa, kb, sa[n], 0, 0, 0);
    }
  }
  #pragma unroll
  for (int n = 0; n < 4; ++n)
    #pragma unroll
    for (int i = 0; i < 4; ++i) {
      const int row = w * 16 + fg * 4 + i, col = n * 16 + fr;
      S[row][col] = (row >= col) ? sa[n][i] * 0.03125f : -1e30f;
    }
  __syncthreads();

  const int c = t & 63, q4 = t >> 6;
  float mx = -1e30f;
  float e[16];
  #pragma unroll
  for (int i = 0; i < 16; ++i) mx = fmaxf(mx, S[q4 * 16 + i][c]);
  red[q4][c] = mx;
  __syncthreads();
  mx = fmaxf(fmaxf(red[0][c], red[1][c]), fmaxf(red[2][c], red[3][c]));
  float sum = 0.f;
  #pragma unroll
  for (int i = 0; i < 16; ++i) { e[i] = __expf(S[q4 * 16 + i][c] - mx); sum += e[i]; }
  __syncthreads();
  red[q4][c] = sum;
  __syncthreads();
  sum = red[0][c] + red[1][c] + red[2][c] + red[3][c];
  const float inv = 1.0f / sum;
  u16 (*P)[72] = qs;
  #pragma unroll
  for (int i = 0; i < 16; ++i)
    P[q4 * 16 + i][c] = f2bf(e[i] * inv);
  __syncthreads();

  f32x4 oa[4] = {};
  #pragma unroll
  for (int kk = 0; kk < 64; kk += 32) {
    bf16x8 pa = *(const bf16x8*)&P[w * 16 + fr][kk + fg * 8];
    #pragma unroll
    for (int n = 0; n < 4; ++n) {
      bf16x8 vb = *(const bf16x8*)&vts[n * 16 + fr][kk + fg * 8];
      oa[n] = __builtin_amdgcn_mfma_f32_16x16x32_bf16(pa, vb, oa[n], 0, 0, 0);
    }
  }
  #pragma unroll
  for (int n = 0; n < 4; ++n)
    #pragma unroll
    for (int i = 0; i < 4; ++i) {
      const int row = w * 16 + fg * 4 + i, col = n * 16 + fr;
      y[(size_t)(b * 64 + row) * 1024 + h * 64 + col] = f2bf(oa[n][i]);
    }
}

// ---------------- final LayerNorm (bf16 in, bf16 out) ----------------
__global__ void __launch_bounds__(256)
ln_kernel(const u16* __restrict__ x, const float* __restrict__ g,
          const float* __restrict__ bb, u16* __restrict__ xn) {
  __shared__ float sred[8];
  const int tok = blockIdx.x;
  const int t = threadIdx.x;
  const ushort4 raw = ((const ushort4*)(x + (size_t)tok * 1024))[t];
  const float v0 = bf2f(raw.x), v1 = bf2f(raw.y), v2 = bf2f(raw.z), v3 = bf2f(raw.w);
  float s  = v0 + v1 + v2 + v3;
  float ss = v0 * v0 + v1 * v1 + v2 * v2 + v3 * v3;
  #pragma unroll
  for (int o = 32; o > 0; o >>= 1) {
    s  += __shfl_xor(s, o);
    ss += __shfl_xor(ss, o);
  }
  const int w = t >> 6;
  if ((t & 63) == 0) { sred[w] = s; sred[4 + w] = ss; }
  __syncthreads();
  s  = sred[0] + sred[1] + sred[2] + sred[3];
  ss = sred[4] + sred[5] + sred[6] + sred[7];
  const float mu = s * (1.0f / 1024.0f);
  const float var = ss * (1.0f / 1024.0f) - mu * mu;
  const float rs = rsqrtf(var + 1e-5f);
  const float4 gg = ((const float4*)g)[t];
  const float4 b4 = ((const float4*)bb)[t];
  u16* o = xn + (size_t)tok * 1024 + t * 4;
  o[0] = f2bf((v0 - mu) * rs * gg.x + b4.x);
  o[1] = f2bf((v1 - mu) * rs * gg.y + b4.y);
  o[2] = f2bf((v2 - mu) * rs * gg.z + b4.z);
  o[3] = f2bf((v3 - mu) * rs * gg.w + b4.w);
}

// ---------------- host ----------------
extern "C" void kernel_launch(void* const* d_in, const int* in_sizes, int n_in,
                              void* d_out, int out_size, void* d_ws, size_t ws_size,
                              hipStream_t stream) {
  const int*   idx     = (const int*)  d_in[0];
  const float* tok_emb = (const float*)d_in[1];
  const float* pos_emb = (const float*)d_in[2];
  const float* wqkv    = (const float*)d_in[3];
  const float* bqkv    = (const float*)d_in[4];
  const float* wo      = (const float*)d_in[5];
  const float* bo      = (const float*)d_in[6];
  const float* w1      = (const float*)d_in[7];
  const float* b1      = (const float*)d_in[8];
  const float* w2      = (const float*)d_in[9];
  const float* b2      = (const float*)d_in[10];
  const float* ln_g    = (const float*)d_in[11];
  const float* ln_b    = (const float*)d_in[12];
  const float* out_w   = (const float*)d_in[13];
  const float* out_b   = (const float*)d_in[14];

  char* p = (char*)d_ws;
  auto take = [&](size_t n) { char* r = p; p += (n + 255) & ~(size_t)255; return r; };
  u16*   wqkv_t = (u16*)  take((size_t)1024 * 3072 * 2);
  u16*   wo_t   = (u16*)  take((size_t)1024 * 1024 * 2);
  u16*   w1_t   = (u16*)  take((size_t)1024 * 4096 * 2);
  u16*   w2_t   = (u16*)  take((size_t)4096 * 1024 * 2);
  u16*   wout_t = (u16*)  take((size_t)1024 * 1024 * 2);
  u16*   xb     = (u16*)  take((size_t)MT * 1024 * 2);   // bf16 residual stream
  u16*   yb     = (u16*)  take((size_t)MT * 1024 * 2);   // attn out / LN out
  u16*   big    = (u16*)  take((size_t)MT * 4096 * 2);   // qkv / h

  const dim3 tb(32, 8);
  embed_kernel<<<MT, 256, 0, stream>>>(idx, tok_emb, pos_emb, xb);

  for (int l = 0; l < 12; ++l) {
    transpose_cvt<<<dim3(3072 / 32, 1024 / 32), tb, 0, stream>>>(
        wqkv + (size_t)l * 1024 * 3072, wqkv_t, 1024, 3072);
    transpose_cvt<<<dim3(1024 / 32, 1024 / 32), tb, 0, stream>>>(
        wo + (size_t)l * 1024 * 1024, wo_t, 1024, 1024);
    transpose_cvt<<<dim3(4096 / 32, 1024 / 32), tb, 0, stream>>>(
        w1 + (size_t)l * 1024 * 4096, w1_t, 1024, 4096);
    transpose_cvt<<<dim3(1024 / 32, 4096 / 32), tb, 0, stream>>>(
        w2 + (size_t)l * 4096 * 1024, w2_t, 4096, 1024);

    gemm256<0><<<(MT / 256) * (3072 / 256), 512, 0, stream>>>(
        xb, wqkv_t, bqkv + (size_t)l * 3072,
        nullptr, big, nullptr, MT, 3072, 1024, 3072 / 256);
    attn_kernel<<<dim3(16, 256), 256, 0, stream>>>(big, yb);
    gemm256<2><<<(MT / 256) * (1024 / 256), 512, 0, stream>>>(
        yb, wo_t, bo + (size_t)l * 1024,
        xb, nullptr, nullptr, MT, 1024, 1024, 1024 / 256);
    gemm256<1><<<(MT / 256) * (4096 / 256), 512, 0, stream>>>(
        xb, w1_t, b1 + (size_t)l * 4096,
        nullptr, big, nullptr, MT, 4096, 1024, 4096 / 256);
    gemm128<2><<<(MT / 128) * (1024 / 128), 256, 0, stream>>>(
        big, w2_t, b2 + (size_t)l * 1024,
        xb, nullptr, nullptr, MT, 1024, 4096, 1024 / 128);
  }

  transpose_cvt<<<dim3(1024 / 32, 1024 / 32), tb, 0, stream>>>(out_w, wout_t, 1024, 1024);
  ln_kernel<<<MT, 256, 0, stream>>>(xb, ln_g, ln_b, yb);
  gemm256<3><<<(MT / 256) * (1024 / 256), 512, 0, stream>>>(
      yb, wout_t, out_b, nullptr, nullptr, (float*)d_out, MT, 1024, 1024, 1024 / 256);
}

// Round 13
// 6222.209 us; speedup vs baseline: 1.3273x; 1.0656x over previous
//
#include <hip/hip_runtime.h>
#include <stdint.h>

typedef unsigned short u16;
typedef __bf16 bf16x8 __attribute__((ext_vector_type(8)));
typedef float f32x4 __attribute__((ext_vector_type(4)));

#define MT 16384   // BATCH*SEQ tokens

__device__ __forceinline__ u16 f2bf(float f) {
  union { float f; unsigned u; } x; x.f = f;
  unsigned r = x.u + 0x7fffu + ((x.u >> 16) & 1u);   // RNE
  return (u16)(r >> 16);
}
__device__ __forceinline__ float bf2f(u16 b) {
  union { float f; unsigned u; } x; x.u = ((unsigned)b) << 16;
  return x.f;
}

#pragma clang diagnostic push
#pragma clang diagnostic ignored "-Waddress-space-conversion"
typedef __attribute__((address_space(1))) unsigned as1u;
typedef __attribute__((address_space(3))) unsigned as3u;
// async global->LDS, 16B per lane; lbase must be wave-uniform (HW adds lane*16)
__device__ __forceinline__ void stage16(const u16* g, const u16* lbase) {
  __builtin_amdgcn_global_load_lds((as1u*)g, (as3u*)lbase, 16, 0, 0);
}
#pragma clang diagnostic pop

// ---------------- weight transpose + f32->bf16 convert (batched over layers) ----------------
__global__ void __launch_bounds__(256)
transpose_cvt(const float* __restrict__ in, u16* __restrict__ out, int K, int N) {
  __shared__ float tile[32][33];
  const size_t zoff = (size_t)blockIdx.z * K * N;
  in  += zoff;
  out += zoff;
  const int k0 = blockIdx.y * 32, n0 = blockIdx.x * 32;
  const int tx = threadIdx.x, ty = threadIdx.y;   // block (32,8)
  #pragma unroll
  for (int r = 0; r < 32; r += 8)
    tile[ty + r][tx] = in[(size_t)(k0 + ty + r) * N + n0 + tx];
  __syncthreads();
  #pragma unroll
  for (int r = 0; r < 32; r += 8)
    out[(size_t)(n0 + ty + r) * K + k0 + tx] = f2bf(tile[tx][ty + r]);
}

// ---------------- embedding: xb = bf16(tok_emb[idx] + pos_emb) ----------------
__global__ void __launch_bounds__(256)
embed_kernel(const int* __restrict__ idx, const float* __restrict__ tok,
             const float* __restrict__ pos, u16* __restrict__ xb) {
  const int tk = blockIdx.x;
  const int s = tk & 63;
  const int id = idx[tk];
  const int t = threadIdx.x;
  float4 a = ((const float4*)(tok + (size_t)id * 1024))[t];
  float4 p = ((const float4*)(pos + (size_t)s * 1024))[t];
  u16* o = xb + (size_t)tk * 1024 + t * 4;
  o[0] = f2bf(a.x + p.x); o[1] = f2bf(a.y + p.y);
  o[2] = f2bf(a.z + p.z); o[3] = f2bf(a.w + p.w);
}

// ------------- 256x256 GEMM: C = A @ Bt^T + bias (QKV / W1) -------------
// 8 waves (2Mx4N), BK=64, double-buffered 128KiB LDS, XOR-swizzled reads,
// inverse-swizzled global_load_lds sources, XCD-aware block swizzle.
// EPI 0: out bf16 | 1: gelu->bf16 | 2: res-bf16 in-place | 3: out f32
template<int EPI>
__global__ void __launch_bounds__(512, 2)
gemm256(const u16* __restrict__ A, const u16* __restrict__ Bt,
        const float* __restrict__ bias, u16* __restrict__ resb,
        u16* __restrict__ outb, float* __restrict__ outf,
        int M, int N, int K, int gn) {
  __shared__ __align__(16) u16 lds[2][2][16384];   // [buf][A|B][256*64]
  const int t = threadIdx.x;
  const int lane = t & 63, w = t >> 6;
  const int wr = w >> 2, wc = w & 3;
  const int fr = lane & 15, fg = lane >> 4;

  const int nwg = gridDim.x;
  const int bid = blockIdx.x;
  const int s = (bid & 7) * (nwg >> 3) + (bid >> 3);
  const int tn = s % gn, tm = s / gn;
  const int m0 = tm * 256, n0 = tn * 256;

  const int srow = w * 8 + (lane >> 3);
  const int sg = (lane & 7) ^ (lane >> 3);
  const u16* gA[4]; const u16* gB[4];
  #pragma unroll
  for (int c = 0; c < 4; ++c) {
    gA[c] = A  + (size_t)(m0 + c * 64 + srow) * K + sg * 8;
    gB[c] = Bt + (size_t)(n0 + c * 64 + srow) * K + sg * 8;
  }
  const int lofs = w * 512;

  f32x4 acc[8][4] = {};
  const int NT = K >> 6;

  #pragma unroll
  for (int c = 0; c < 4; ++c) {
    stage16(gA[c], &lds[0][0][lofs + c * 4096]);
    stage16(gB[c], &lds[0][1][lofs + c * 4096]);
  }
  __syncthreads();

  int cur = 0;
  for (int kt = 0; kt < NT; ++kt) {
    if (kt + 1 < NT) {
      const int koff = (kt + 1) << 6;
      #pragma unroll
      for (int c = 0; c < 4; ++c) {
        stage16(gA[c] + koff, &lds[cur ^ 1][0][lofs + c * 4096]);
        stage16(gB[c] + koff, &lds[cur ^ 1][1][lofs + c * 4096]);
      }
    }
    #pragma unroll
    for (int h = 0; h < 2; ++h) {
      bf16x8 af[8], bv[4];
      #pragma unroll
      for (int m = 0; m < 8; ++m) {
        const int row = wr * 128 + m * 16 + fr;
        const int g = (fg + h * 4) ^ (fr & 7);
        af[m] = *(const bf16x8*)&lds[cur][0][row * 64 + g * 8];
      }
      #pragma unroll
      for (int n = 0; n < 4; ++n) {
        const int row = wc * 64 + n * 16 + fr;
        const int g = (fg + h * 4) ^ (fr & 7);
        bv[n] = *(const bf16x8*)&lds[cur][1][row * 64 + g * 8];
      }
      #pragma unroll
      for (int m = 0; m < 8; ++m)
        #pragma unroll
        for (int n = 0; n < 4; ++n)
          acc[m][n] = __builtin_amdgcn_mfma_f32_16x16x32_bf16(af[m], bv[n], acc[m][n], 0, 0, 0);
    }
    __syncthreads();
    cur ^= 1;
  }

  #pragma unroll
  for (int m = 0; m < 8; ++m) {
    const int row = m0 + wr * 128 + m * 16 + fg * 4;
    #pragma unroll
    for (int n = 0; n < 4; ++n) {
      const int col = n0 + wc * 64 + n * 16 + fr;
      const float bc = bias[col];
      #pragma unroll
      for (int i = 0; i < 4; ++i) {
        const size_t off = (size_t)(row + i) * N + col;
        float v = acc[m][n][i] + bc;
        if constexpr (EPI == 0) {
          outb[off] = f2bf(v);
        } else if constexpr (EPI == 1) {
          v = 0.5f * v * (1.0f + erff(v * 0.70710678118654752f));
          outb[off] = f2bf(v);
        } else if constexpr (EPI == 2) {
          v += bf2f(resb[off]);
          resb[off] = f2bf(v);
        } else {
          outf[off] = v;
        }
      }
    }
  }
}

// ---------------- 128x128 GEMM (WO / W2 / final) ----------------
template<int EPI>
__global__ void __launch_bounds__(256, 3)
gemm128(const u16* __restrict__ A, const u16* __restrict__ Bt,
        const float* __restrict__ bias, u16* __restrict__ resb,
        u16* __restrict__ outb, float* __restrict__ outf,
        int M, int N, int K, int gn) {
  __shared__ __align__(16) u16 lA[2][4096];   // 128 rows x 32 k bf16 per buffer
  __shared__ __align__(16) u16 lB[2][4096];
  const int t = threadIdx.x;
  const int lane = t & 63, w = t >> 6;
  const int wr = w >> 1, wc = w & 1;
  const int fr = lane & 15, fg = lane >> 4;

  const int nwg = gridDim.x;
  const int bid = blockIdx.x;
  const int s = (bid & 7) * (nwg >> 3) + (bid >> 3);
  const int tn = s % gn, tm = s / gn;
  const int m0 = tm * 128, n0 = tn * 128;

  const int rin = ((lane >> 3) << 1) + ((lane >> 2) & 1);
  const int fgl = (lane & 3) ^ ((lane >> 3) & 3);
  const u16* gA[2]; const u16* gB[2];
  #pragma unroll
  for (int i = 0; i < 2; ++i) {
    gA[i] = A  + (size_t)(m0 + (w * 2 + i) * 16 + rin) * K + fgl * 8;
    gB[i] = Bt + (size_t)(n0 + (w * 2 + i) * 16 + rin) * K + fgl * 8;
  }

  const int sub8 = ((fr & 1) * 4 + (fg ^ ((fr >> 1) & 3))) * 8;
  const int ar = wr * 2048 + (fr >> 1) * 64 + sub8;
  const int br = wc * 2048 + (fr >> 1) * 64 + sub8;

  f32x4 acc[4][4] = {};
  const int NT = K >> 5;

  #pragma unroll
  for (int i = 0; i < 2; ++i) {
    stage16(gA[i], &lA[0][(w * 2 + i) * 512]);
    stage16(gB[i], &lB[0][(w * 2 + i) * 512]);
  }
  __syncthreads();

  int cur = 0;
  for (int kt = 0; kt < NT; ++kt) {
    if (kt + 1 < NT) {
      const int ko = (kt + 1) << 5;
      #pragma unroll
      for (int i = 0; i < 2; ++i) {
        stage16(gA[i] + ko, &lA[cur ^ 1][(w * 2 + i) * 512]);
        stage16(gB[i] + ko, &lB[cur ^ 1][(w * 2 + i) * 512]);
      }
    }
    bf16x8 af[4], bv[4];
    #pragma unroll
    for (int m = 0; m < 4; ++m) af[m] = *(const bf16x8*)&lA[cur][ar + m * 512];
    #pragma unroll
    for (int n = 0; n < 4; ++n) bv[n] = *(const bf16x8*)&lB[cur][br + n * 512];
    #pragma unroll
    for (int m = 0; m < 4; ++m)
      #pragma unroll
      for (int n = 0; n < 4; ++n)
        acc[m][n] = __builtin_amdgcn_mfma_f32_16x16x32_bf16(af[m], bv[n], acc[m][n], 0, 0, 0);
    __syncthreads();
    cur ^= 1;
  }

  #pragma unroll
  for (int m = 0; m < 4; ++m) {
    const int row = m0 + wr * 64 + m * 16 + fg * 4;
    #pragma unroll
    for (int n = 0; n < 4; ++n) {
      const int col = n0 + wc * 64 + n * 16 + fr;
      const float bc = bias[col];
      #pragma unroll
      for (int i = 0; i < 4; ++i) {
        const size_t off = (size_t)(row + i) * N + col;
        float v = acc[m][n][i] + bc;
        if constexpr (EPI == 0) {
          outb[off] = f2bf(v);
        } else if constexpr (EPI == 1) {
          v = 0.5f * v * (1.0f + erff(v * 0.70710678118654752f));
          outb[off] = f2bf(v);
        } else if constexpr (EPI == 2) {
          v += bf2f(resb[off]);
          resb[off] = f2bf(v);
        } else {
          outf[off] = v;
        }
      }
    }
  }
}

// ---------------- attention (one block per (b,h)) ----------------
__global__ void __launch_bounds__(256)
attn_kernel(const u16* __restrict__ qkv, u16* __restrict__ y) {
  __shared__ __align__(16) u16 qs[64][72];    // Q; reused as P (bf16)
  __shared__ __align__(16) u16 ks[64][72];
  __shared__ __align__(16) u16 vts[64][72];   // V transposed: [dh][key]
  __shared__ __align__(16) float S[64][68];   // [query][key] f32
  __shared__ float red[4][64];

  const int h = blockIdx.x, b = blockIdx.y;
  const int t = threadIdx.x;
  const int lane = t & 63, w = t >> 6;
  const int fr = lane & 15, fg = lane >> 4;

  #pragma unroll
  for (int it = 0; it < 2; ++it) {
    const int id = t + it * 256;           // 0..511
    const int row = id >> 3, seg = id & 7;
    const size_t gq = (size_t)(b * 64 + row) * 3072 + h * 64 + seg * 8;
    *(uint4*)&qs[row][seg * 8] = *(const uint4*)&qkv[gq];
    *(uint4*)&ks[row][seg * 8] = *(const uint4*)&qkv[gq + 1024];
  }
  {
    const int d = t & 63;
    #pragma unroll
    for (int it = 0; it < 16; ++it) {
      const int s = (t >> 6) + it * 4;
      vts[d][s] = qkv[(size_t)(b * 64 + s) * 3072 + 2048 + h * 64 + d];
    }
  }
  __syncthreads();

  f32x4 sa[4] = {};
  #pragma unroll
  for (int kk = 0; kk < 64; kk += 32) {
    bf16x8 qa = *(const bf16x8*)&qs[w * 16 + fr][kk + fg * 8];
    #pragma unroll
    for (int n = 0; n < 4; ++n) {
      bf16x8 kb = *(const bf16x8*)&ks[n * 16 + fr][kk + fg * 8];
      sa[n] = __builtin_amdgcn_mfma_f32_16x16x32_bf16(qa, kb, sa[n], 0, 0, 0);
    }
  }
  #pragma unroll
  for (int n = 0; n < 4; ++n)
    #pragma unroll
    for (int i = 0; i < 4; ++i) {
      const int row = w * 16 + fg * 4 + i, col = n * 16 + fr;
      S[row][col] = (row >= col) ? sa[n][i] * 0.03125f : -1e30f;
    }
  __syncthreads();

  const int c = t & 63, q4 = t >> 6;
  float mx = -1e30f;
  float e[16];
  #pragma unroll
  for (int i = 0; i < 16; ++i) mx = fmaxf(mx, S[q4 * 16 + i][c]);
  red[q4][c] = mx;
  __syncthreads();
  mx = fmaxf(fmaxf(red[0][c], red[1][c]), fmaxf(red[2][c], red[3][c]));
  float sum = 0.f;
  #pragma unroll
  for (int i = 0; i < 16; ++i) { e[i] = __expf(S[q4 * 16 + i][c] - mx); sum += e[i]; }
  __syncthreads();
  red[q4][c] = sum;
  __syncthreads();
  sum = red[0][c] + red[1][c] + red[2][c] + red[3][c];
  const float inv = 1.0f / sum;
  u16 (*P)[72] = qs;
  #pragma unroll
  for (int i = 0; i < 16; ++i)
    P[q4 * 16 + i][c] = f2bf(e[i] * inv);
  __syncthreads();

  f32x4 oa[4] = {};
  #pragma unroll
  for (int kk = 0; kk < 64; kk += 32) {
    bf16x8 pa = *(const bf16x8*)&P[w * 16 + fr][kk + fg * 8];
    #pragma unroll
    for (int n = 0; n < 4; ++n) {
      bf16x8 vb = *(const bf16x8*)&vts[n * 16 + fr][kk + fg * 8];
      oa[n] = __builtin_amdgcn_mfma_f32_16x16x32_bf16(pa, vb, oa[n], 0, 0, 0);
    }
  }
  #pragma unroll
  for (int n = 0; n < 4; ++n)
    #pragma unroll
    for (int i = 0; i < 4; ++i) {
      const int row = w * 16 + fg * 4 + i, col = n * 16 + fr;
      y[(size_t)(b * 64 + row) * 1024 + h * 64 + col] = f2bf(oa[n][i]);
    }
}

// ---------------- final LayerNorm (bf16 in, bf16 out) ----------------
__global__ void __launch_bounds__(256)
ln_kernel(const u16* __restrict__ x, const float* __restrict__ g,
          const float* __restrict__ bb, u16* __restrict__ xn) {
  __shared__ float sred[8];
  const int tok = blockIdx.x;
  const int t = threadIdx.x;
  const ushort4 raw = ((const ushort4*)(x + (size_t)tok * 1024))[t];
  const float v0 = bf2f(raw.x), v1 = bf2f(raw.y), v2 = bf2f(raw.z), v3 = bf2f(raw.w);
  float s  = v0 + v1 + v2 + v3;
  float ss = v0 * v0 + v1 * v1 + v2 * v2 + v3 * v3;
  #pragma unroll
  for (int o = 32; o > 0; o >>= 1) {
    s  += __shfl_xor(s, o);
    ss += __shfl_xor(ss, o);
  }
  const int w = t >> 6;
  if ((t & 63) == 0) { sred[w] = s; sred[4 + w] = ss; }
  __syncthreads();
  s  = sred[0] + sred[1] + sred[2] + sred[3];
  ss = sred[4] + sred[5] + sred[6] + sred[7];
  const float mu = s * (1.0f / 1024.0f);
  const float var = ss * (1.0f / 1024.0f) - mu * mu;
  const float rs = rsqrtf(var + 1e-5f);
  const float4 gg = ((const float4*)g)[t];
  const float4 b4 = ((const float4*)bb)[t];
  u16* o = xn + (size_t)tok * 1024 + t * 4;
  o[0] = f2bf((v0 - mu) * rs * gg.x + b4.x);
  o[1] = f2bf((v1 - mu) * rs * gg.y + b4.y);
  o[2] = f2bf((v2 - mu) * rs * gg.z + b4.z);
  o[3] = f2bf((v3 - mu) * rs * gg.w + b4.w);
}

// ---------------- host ----------------
extern "C" void kernel_launch(void* const* d_in, const int* in_sizes, int n_in,
                              void* d_out, int out_size, void* d_ws, size_t ws_size,
                              hipStream_t stream) {
  const int*   idx     = (const int*)  d_in[0];
  const float* tok_emb = (const float*)d_in[1];
  const float* pos_emb = (const float*)d_in[2];
  const float* wqkv    = (const float*)d_in[3];
  const float* bqkv    = (const float*)d_in[4];
  const float* wo      = (const float*)d_in[5];
  const float* bo      = (const float*)d_in[6];
  const float* w1      = (const float*)d_in[7];
  const float* b1      = (const float*)d_in[8];
  const float* w2      = (const float*)d_in[9];
  const float* b2      = (const float*)d_in[10];
  const float* ln_g    = (const float*)d_in[11];
  const float* ln_b    = (const float*)d_in[12];
  const float* out_w   = (const float*)d_in[13];
  const float* out_b   = (const float*)d_in[14];

  // workspace (~500 MB): ALL weights converted up-front (batched z=12)
  char* p = (char*)d_ws;
  auto take = [&](size_t n) { char* r = p; p += (n + 255) & ~(size_t)255; return r; };
  u16*   wqkv_t = (u16*)  take((size_t)12 * 1024 * 3072 * 2);
  u16*   wo_t   = (u16*)  take((size_t)12 * 1024 * 1024 * 2);
  u16*   w1_t   = (u16*)  take((size_t)12 * 1024 * 4096 * 2);
  u16*   w2_t   = (u16*)  take((size_t)12 * 4096 * 1024 * 2);
  u16*   wout_t = (u16*)  take((size_t)1024 * 1024 * 2);
  u16*   xb     = (u16*)  take((size_t)MT * 1024 * 2);   // bf16 residual stream
  u16*   yb     = (u16*)  take((size_t)MT * 1024 * 2);   // attn out / LN out
  u16*   big    = (u16*)  take((size_t)MT * 4096 * 2);   // qkv / h

  const dim3 tb(32, 8);
  // prologue: all weight conversions in 5 launches
  transpose_cvt<<<dim3(3072 / 32, 1024 / 32, 12), tb, 0, stream>>>(wqkv, wqkv_t, 1024, 3072);
  transpose_cvt<<<dim3(1024 / 32, 1024 / 32, 12), tb, 0, stream>>>(wo,   wo_t,   1024, 1024);
  transpose_cvt<<<dim3(4096 / 32, 1024 / 32, 12), tb, 0, stream>>>(w1,   w1_t,   1024, 4096);
  transpose_cvt<<<dim3(1024 / 32, 4096 / 32, 12), tb, 0, stream>>>(w2,   w2_t,   4096, 1024);
  transpose_cvt<<<dim3(1024 / 32, 1024 / 32, 1),  tb, 0, stream>>>(out_w, wout_t, 1024, 1024);

  embed_kernel<<<MT, 256, 0, stream>>>(idx, tok_emb, pos_emb, xb);

  for (int l = 0; l < 12; ++l) {
    gemm256<0><<<(MT / 256) * (3072 / 256), 512, 0, stream>>>(
        xb, wqkv_t + (size_t)l * 3072 * 1024, bqkv + (size_t)l * 3072,
        nullptr, big, nullptr, MT, 3072, 1024, 3072 / 256);
    attn_kernel<<<dim3(16, 256), 256, 0, stream>>>(big, yb);
    gemm128<2><<<(MT / 128) * (1024 / 128), 256, 0, stream>>>(
        yb, wo_t + (size_t)l * 1024 * 1024, bo + (size_t)l * 1024,
        xb, nullptr, nullptr, MT, 1024, 1024, 1024 / 128);
    gemm256<1><<<(MT / 256) * (4096 / 256), 512, 0, stream>>>(
        xb, w1_t + (size_t)l * 1024 * 4096, b1 + (size_t)l * 4096,
        nullptr, big, nullptr, MT, 4096, 1024, 4096 / 256);
    gemm128<2><<<(MT / 128) * (1024 / 128), 256, 0, stream>>>(
        big, w2_t + (size_t)l * 4096 * 1024, b2 + (size_t)l * 1024,
        xb, nullptr, nullptr, MT, 1024, 4096, 1024 / 128);
  }

  ln_kernel<<<MT, 256, 0, stream>>>(xb, ln_g, ln_b, yb);
  gemm128<3><<<(MT / 128) * (1024 / 128), 256, 0, stream>>>(
      yb, wout_t, out_b, nullptr, nullptr, (float*)d_out, MT, 1024, 1024, 1024 / 128);
}